// Round 1
// baseline (404.427 us; speedup 1.0000x reference)
//
#include <hip/hip_runtime.h>
#include <hip/hip_bf16.h>

#define AS1 __attribute__((address_space(1)))
#define AS3 __attribute__((address_space(3)))

typedef __attribute__((ext_vector_type(8))) short bfrag8;   // 8 bf16 in 4 VGPRs
typedef __attribute__((ext_vector_type(4))) float floatx4;  // MFMA accumulator

static constexpr int M = 4096, N = 4096, K = 4096;
static constexpr long long NELEM = 16777216LL;  // 4096*4096 (both |x| and |W| counts)

// ---------- round-to-nearest-even fp32 -> bf16 ----------
__device__ __forceinline__ unsigned short f2bf(float f) {
    unsigned int u = __float_as_uint(f);
    u += 0x7FFFu + ((u >> 16) & 1u);
    return (unsigned short)(u >> 16);
}

// ---------- block+wave reduce (double) then atomicAdd ----------
__device__ __forceinline__ void block_reduce_atomic(double s, double* out) {
    #pragma unroll
    for (int off = 32; off > 0; off >>= 1) s += __shfl_down(s, off, 64);
    __shared__ double part[4];
    int lane = threadIdx.x & 63, wv = threadIdx.x >> 6;
    if (lane == 0) part[wv] = s;
    __syncthreads();
    if (threadIdx.x == 0) atomicAdd(out, part[0] + part[1] + part[2] + part[3]);
}

// ---------- fused: sum|x| (double) + convert x -> bf16 ----------
__global__ void reduce_convert_x(const float* __restrict__ x,
                                 unsigned short* __restrict__ xb,
                                 double* __restrict__ sum_x) {
    long long idx = (long long)blockIdx.x * blockDim.x + threadIdx.x;
    long long stride = (long long)gridDim.x * blockDim.x;
    const float4* x4 = (const float4*)x;
    ushort4* xb4 = (ushort4*)xb;
    long long n4 = NELEM / 4;
    double s = 0.0;
    for (long long i = idx; i < n4; i += stride) {
        float4 v = x4[i];
        s += (double)fabsf(v.x); s += (double)fabsf(v.y);
        s += (double)fabsf(v.z); s += (double)fabsf(v.w);
        ushort4 r;
        r.x = f2bf(v.x); r.y = f2bf(v.y); r.z = f2bf(v.z); r.w = f2bf(v.w);
        xb4[i] = r;
    }
    block_reduce_atomic(s, sum_x);
}

// ---------- sum|W| (double) ----------
__global__ void reduce_abs_w(const float* __restrict__ w, double* __restrict__ sum_w) {
    long long idx = (long long)blockIdx.x * blockDim.x + threadIdx.x;
    long long stride = (long long)gridDim.x * blockDim.x;
    const float4* w4 = (const float4*)w;
    long long n4 = NELEM / 4;
    double s = 0.0;
    for (long long i = idx; i < n4; i += stride) {
        float4 v = w4[i];
        s += (double)fabsf(v.x); s += (double)fabsf(v.y);
        s += (double)fabsf(v.z); s += (double)fabsf(v.w);
    }
    block_reduce_atomic(s, sum_w);
}

// ---------- ternary quantize W -> bf16 {-1,0,+1} ----------
__device__ __forceinline__ unsigned short tq(float v, float scale_f) {
    float wn = v / scale_f;                       // match reference fp32 division
    if (fabsf(wn) > 0.5f)
        return (unsigned short)(0x3F80u | ((__float_as_uint(v) >> 16) & 0x8000u));
    return 0;
}

__global__ void quantize_w(const float* __restrict__ w,
                           unsigned short* __restrict__ qb,
                           const double* __restrict__ sum_w) {
    float scale_f = (float)fmax(*sum_w / (double)NELEM, 1e-8);
    long long idx = (long long)blockIdx.x * blockDim.x + threadIdx.x;
    long long stride = (long long)gridDim.x * blockDim.x;
    const float4* w4 = (const float4*)w;
    ushort4* q4 = (ushort4*)qb;
    long long n4 = NELEM / 4;
    for (long long i = idx; i < n4; i += stride) {
        float4 v = w4[i];
        ushort4 r;
        r.x = tq(v.x, scale_f); r.y = tq(v.y, scale_f);
        r.z = tq(v.z, scale_f); r.w = tq(v.w, scale_f);
        q4[i] = r;
    }
}

// ---------- m97-style bf16 GEMM: out[m][n] = sum_k A[m][k]*B[n][k] ----------
// A = x_bf16 [M][K], B = q_bf16 [N][K] (both K-contiguous -> "B^T" layout)
__global__ __launch_bounds__(256) void gemm_bt(
        const unsigned short* __restrict__ A,
        const unsigned short* __restrict__ B,
        const float* __restrict__ bias,
        const double* __restrict__ sums,   // [0]=sum|x|, [1]=sum|W|
        float* __restrict__ out) {
    __shared__ unsigned short lds[2 * 128 * 64];  // A tile 16KB + B tile 16KB
    unsigned short* ldsA = lds;
    unsigned short* ldsB = lds + 128 * 64;

    const int tid = threadIdx.x;
    const int lane = tid & 63;
    const int wv = tid >> 6;            // wave 0..3
    const int wm = wv & 1;              // wave row (2x2 wave grid, 64x64 each)
    const int wn = wv >> 1;
    const int col16 = lane & 15;
    const int quad = lane >> 4;

    const int m0 = blockIdx.y * 128;
    const int n0 = blockIdx.x * 128;

    // staging geometry: chunk c = wv*4+j covers 8 rows; lane covers 16B
    const int srow = lane >> 3;          // 0..7 within chunk
    const int scol = (lane & 7) * 8;     // k-element offset within 64

    floatx4 acc[4][4];
    #pragma unroll
    for (int i = 0; i < 4; i++)
        #pragma unroll
        for (int j = 0; j < 4; j++)
            acc[i][j] = (floatx4)0.0f;

    for (int k0 = 0; k0 < K; k0 += 64) {
        #pragma unroll
        for (int j = 0; j < 4; j++) {
            const int c = wv * 4 + j;            // 0..15
            const int row = c * 8 + srow;        // 0..127
            const unsigned short* ga = A + (size_t)(m0 + row) * K + k0 + scol;
            const unsigned short* gb = B + (size_t)(n0 + row) * K + k0 + scol;
            char* la = (char*)lds + c * 1024 + lane * 16;
            char* lb = (char*)lds + 16384 + c * 1024 + lane * 16;
            __builtin_amdgcn_global_load_lds((const AS1 void*)ga, (AS3 void*)la, 16, 0, 0);
            __builtin_amdgcn_global_load_lds((const AS1 void*)gb, (AS3 void*)lb, 16, 0, 0);
        }
        __syncthreads();   // drains vmcnt before barrier (compiler-inserted)

        #pragma unroll
        for (int kk = 0; kk < 64; kk += 32) {
            bfrag8 af[4], bf[4];
            #pragma unroll
            for (int i = 0; i < 4; i++) {
                af[i] = *(const bfrag8*)&ldsA[(wm * 64 + i * 16 + col16) * 64 + kk + quad * 8];
                bf[i] = *(const bfrag8*)&ldsB[(wn * 64 + i * 16 + col16) * 64 + kk + quad * 8];
            }
            #pragma unroll
            for (int i = 0; i < 4; i++)
                #pragma unroll
                for (int j = 0; j < 4; j++)
                    acc[i][j] = __builtin_amdgcn_mfma_f32_16x16x32_bf16(af[i], bf[j], acc[i][j], 0, 0, 0);
        }
        __syncthreads();
    }

    const float wscale = (float)fmax(sums[1] / (double)NELEM, 1e-8);
    const float iscale = (float)fmax(sums[0] / (double)NELEM, 1e-8);

    float bv[4];
    #pragma unroll
    for (int j = 0; j < 4; j++)
        bv[j] = bias[n0 + wn * 64 + j * 16 + col16] * iscale;

    #pragma unroll
    for (int i = 0; i < 4; i++) {
        const int mbase = m0 + wm * 64 + i * 16 + quad * 4;
        #pragma unroll
        for (int j = 0; j < 4; j++) {
            const int n = n0 + wn * 64 + j * 16 + col16;
            #pragma unroll
            for (int r = 0; r < 4; r++)
                out[(size_t)(mbase + r) * N + n] = acc[i][j][r] * wscale + bv[j];
        }
    }
}

extern "C" void kernel_launch(void* const* d_in, const int* in_sizes, int n_in,
                              void* d_out, int out_size, void* d_ws, size_t ws_size,
                              hipStream_t stream) {
    const float* x    = (const float*)d_in[0];   // (2,2048,4096) fp32
    const float* w    = (const float*)d_in[1];   // (4096,4096) fp32
    const float* bias = (const float*)d_in[2];   // (4096,) fp32
    float* out = (float*)d_out;                  // (2,2048,4096) fp32

    char* ws = (char*)d_ws;
    double* sums = (double*)ws;                              // [0]=sum|x|, [1]=sum|W|
    unsigned short* xb = (unsigned short*)(ws + 256);        // 32 MB bf16 x
    unsigned short* qb = (unsigned short*)(ws + 256 + (size_t)NELEM * 2);  // 32 MB bf16 qW

    hipMemsetAsync(sums, 0, 16, stream);
    reduce_convert_x<<<2048, 256, 0, stream>>>(x, xb, &sums[0]);
    reduce_abs_w<<<2048, 256, 0, stream>>>(w, &sums[1]);
    quantize_w<<<4096, 256, 0, stream>>>(w, qb, &sums[1]);

    dim3 grid(N / 128, M / 128);
    gemm_bt<<<grid, 256, 0, stream>>>(xb, qb, bias, sums, out);
}

// Round 2
// 335.434 us; speedup vs baseline: 1.2057x; 1.2057x over previous
//
#include <hip/hip_runtime.h>
#include <hip/hip_bf16.h>

#define AS1 __attribute__((address_space(1)))
#define AS3 __attribute__((address_space(3)))

typedef __attribute__((ext_vector_type(8))) short bfrag8;   // 8 bf16 in 4 VGPRs
typedef __attribute__((ext_vector_type(4))) float floatx4;  // MFMA accumulator

static constexpr int M = 4096, N = 4096, K = 4096;
static constexpr long long NELEM = 16777216LL;  // 4096*4096
static constexpr int RBLOCKS = 512;             // reduction grid

// ---------- round-to-nearest-even fp32 -> bf16 ----------
__device__ __forceinline__ unsigned short f2bf(float f) {
    unsigned int u = __float_as_uint(f);
    u += 0x7FFFu + ((u >> 16) & 1u);
    return (unsigned short)(u >> 16);
}

// ---------- block reduce (double) -> one value on thread 0 ----------
__device__ __forceinline__ double block_reduce(double s) {
    #pragma unroll
    for (int off = 32; off > 0; off >>= 1) s += __shfl_down(s, off, 64);
    __shared__ double part[4];
    int lane = threadIdx.x & 63, wv = threadIdx.x >> 6;
    if (lane == 0) part[wv] = s;
    __syncthreads();
    return part[0] + part[1] + part[2] + part[3];
}

// ---------- fused: sum|x| (double partials) + convert x -> bf16 ----------
__global__ void reduce_convert_x(const float* __restrict__ x,
                                 unsigned short* __restrict__ xb,
                                 double* __restrict__ partials) {
    long long idx = (long long)blockIdx.x * blockDim.x + threadIdx.x;
    long long stride = (long long)gridDim.x * blockDim.x;
    const float4* x4 = (const float4*)x;
    ushort4* xb4 = (ushort4*)xb;
    long long n4 = NELEM / 4;
    double s = 0.0;
    for (long long i = idx; i < n4; i += stride) {
        float4 v = x4[i];
        s += (double)fabsf(v.x); s += (double)fabsf(v.y);
        s += (double)fabsf(v.z); s += (double)fabsf(v.w);
        ushort4 r;
        r.x = f2bf(v.x); r.y = f2bf(v.y); r.z = f2bf(v.z); r.w = f2bf(v.w);
        xb4[i] = r;
    }
    double bs = block_reduce(s);
    if (threadIdx.x == 0) partials[blockIdx.x] = bs;
}

// ---------- sum|W| (double partials) ----------
__global__ void reduce_abs_w(const float* __restrict__ w, double* __restrict__ partials) {
    long long idx = (long long)blockIdx.x * blockDim.x + threadIdx.x;
    long long stride = (long long)gridDim.x * blockDim.x;
    const float4* w4 = (const float4*)w;
    long long n4 = NELEM / 4;
    double s = 0.0;
    for (long long i = idx; i < n4; i += stride) {
        float4 v = w4[i];
        s += (double)fabsf(v.x); s += (double)fabsf(v.y);
        s += (double)fabsf(v.z); s += (double)fabsf(v.w);
    }
    double bs = block_reduce(s);
    if (threadIdx.x == 0) partials[blockIdx.x] = bs;
}

// ---------- finalize: partials -> float scales ----------
__global__ void finalize_scales(const double* __restrict__ px,
                                const double* __restrict__ pw,
                                float* __restrict__ scales) {
    int t = threadIdx.x;  // 256 threads
    double sx = px[t] + px[t + 256];
    double sw = pw[t] + pw[t + 256];
    #pragma unroll
    for (int off = 32; off > 0; off >>= 1) {
        sx += __shfl_down(sx, off, 64);
        sw += __shfl_down(sw, off, 64);
    }
    __shared__ double ax[4], aw[4];
    int lane = t & 63, wv = t >> 6;
    if (lane == 0) { ax[wv] = sx; aw[wv] = sw; }
    __syncthreads();
    if (t == 0) {
        double fsx = ax[0] + ax[1] + ax[2] + ax[3];
        double fsw = aw[0] + aw[1] + aw[2] + aw[3];
        scales[0] = (float)fmax(fsw / (double)NELEM, 1e-8);  // weight scale
        scales[1] = (float)fmax(fsx / (double)NELEM, 1e-8);  // input scale
    }
}

// ---------- ternary quantize W -> bf16 {-1,0,+1} ----------
__device__ __forceinline__ unsigned short tq(float v, float scale_f) {
    float wn = v / scale_f;                       // match reference fp32 division
    if (fabsf(wn) > 0.5f)
        return (unsigned short)(0x3F80u | ((__float_as_uint(v) >> 16) & 0x8000u));
    return 0;
}

__global__ void quantize_w(const float* __restrict__ w,
                           unsigned short* __restrict__ qb,
                           const float* __restrict__ scales) {
    float scale_f = scales[0];
    long long idx = (long long)blockIdx.x * blockDim.x + threadIdx.x;
    long long stride = (long long)gridDim.x * blockDim.x;
    const float4* w4 = (const float4*)w;
    ushort4* q4 = (ushort4*)qb;
    long long n4 = NELEM / 4;
    for (long long i = idx; i < n4; i += stride) {
        float4 v = w4[i];
        ushort4 r;
        r.x = tq(v.x, scale_f); r.y = tq(v.y, scale_f);
        r.z = tq(v.z, scale_f); r.w = tq(v.w, scale_f);
        q4[i] = r;
    }
}

// ---------- m97-style bf16 GEMM with XOR-swizzled LDS ----------
// out[m][n] = (sum_k A[m][k]*B[n][k]) * wscale + bias[n]*iscale
// LDS layout: row r (128B) holds its 8 k-chunks permuted: chunk j at slot j^(r&7).
// Staging achieves this by permuting the *global* source per lane (LDS dst is
// forced contiguous by global_load_lds); reads apply the inverse permutation.
// Bank census after swizzle: 8 dword accesses/bank per wave64 b128 read (floor).
__global__ __launch_bounds__(256) void gemm_bt(
        const unsigned short* __restrict__ A,
        const unsigned short* __restrict__ B,
        const float* __restrict__ bias,
        const float* __restrict__ scales,   // [0]=wscale, [1]=iscale
        float* __restrict__ out) {
    __shared__ unsigned short lds[2 * 128 * 64];  // A tile 16KB + B tile 16KB
    const char* ldsA = (const char*)lds;
    const char* ldsB = (const char*)lds + 16384;

    const int tid = threadIdx.x;
    const int lane = tid & 63;
    const int wv = tid >> 6;            // wave 0..3
    const int wm = wv & 1;              // 2x2 wave grid, 64x64 each
    const int wn = wv >> 1;
    const int col16 = lane & 15;
    const int quad = lane >> 4;

    const int m0 = blockIdx.y * 128;
    const int n0 = blockIdx.x * 128;

    // staging: chunk c = wv*4+j covers rows c*8..c*8+7; lane -> 16B
    const int srow = lane >> 3;                      // 0..7 within chunk
    const int scol = ((lane & 7) ^ srow) * 8;        // swizzled k-offset (elements)

    floatx4 acc[4][4];
    #pragma unroll
    for (int i = 0; i < 4; i++)
        #pragma unroll
        for (int j = 0; j < 4; j++)
            acc[i][j] = (floatx4)0.0f;

    for (int k0 = 0; k0 < K; k0 += 64) {
        #pragma unroll
        for (int j = 0; j < 4; j++) {
            const int c = wv * 4 + j;            // 0..15
            const int row = c * 8 + srow;        // 0..127
            const unsigned short* ga = A + (size_t)(m0 + row) * K + k0 + scol;
            const unsigned short* gb = B + (size_t)(n0 + row) * K + k0 + scol;
            char* la = (char*)lds + c * 1024 + lane * 16;
            char* lb = (char*)lds + 16384 + c * 1024 + lane * 16;
            __builtin_amdgcn_global_load_lds((const AS1 void*)ga, (AS3 void*)la, 16, 0, 0);
            __builtin_amdgcn_global_load_lds((const AS1 void*)gb, (AS3 void*)lb, 16, 0, 0);
        }
        __syncthreads();

        #pragma unroll
        for (int kk = 0; kk < 64; kk += 32) {
            const int kc = (kk >> 3) + quad;             // k-chunk index 0..7
            const int sw = (kc ^ (col16 & 7)) << 4;      // swizzled byte offset in row
            bfrag8 af[4], bfr[4];
            #pragma unroll
            for (int i = 0; i < 4; i++) {
                const int ra = wm * 64 + i * 16 + col16;
                const int rb = wn * 64 + i * 16 + col16;
                af[i]  = *(const bfrag8*)(ldsA + ra * 128 + sw);
                bfr[i] = *(const bfrag8*)(ldsB + rb * 128 + sw);
            }
            #pragma unroll
            for (int i = 0; i < 4; i++)
                #pragma unroll
                for (int j = 0; j < 4; j++)
                    acc[i][j] = __builtin_amdgcn_mfma_f32_16x16x32_bf16(af[i], bfr[j], acc[i][j], 0, 0, 0);
        }
        __syncthreads();
    }

    const float wscale = scales[0];
    const float iscale = scales[1];

    float bv[4];
    #pragma unroll
    for (int j = 0; j < 4; j++)
        bv[j] = bias[n0 + wn * 64 + j * 16 + col16] * iscale;

    #pragma unroll
    for (int i = 0; i < 4; i++) {
        const int mbase = m0 + wm * 64 + i * 16 + quad * 4;
        #pragma unroll
        for (int j = 0; j < 4; j++) {
            const int n = n0 + wn * 64 + j * 16 + col16;
            #pragma unroll
            for (int r = 0; r < 4; r++)
                out[(size_t)(mbase + r) * N + n] = acc[i][j][r] * wscale + bv[j];
        }
    }
}

extern "C" void kernel_launch(void* const* d_in, const int* in_sizes, int n_in,
                              void* d_out, int out_size, void* d_ws, size_t ws_size,
                              hipStream_t stream) {
    const float* x    = (const float*)d_in[0];   // (2,2048,4096) fp32
    const float* w    = (const float*)d_in[1];   // (4096,4096) fp32
    const float* bias = (const float*)d_in[2];   // (4096,) fp32
    float* out = (float*)d_out;                  // (2,2048,4096) fp32

    char* ws = (char*)d_ws;
    float*  scales = (float*)ws;                               // 2 floats
    double* px     = (double*)(ws + 256);                      // 512 doubles
    double* pw     = (double*)(ws + 256 + RBLOCKS * 8);        // 512 doubles
    unsigned short* xb = (unsigned short*)(ws + 16384);                         // 32 MB
    unsigned short* qb = (unsigned short*)(ws + 16384 + (size_t)NELEM * 2);     // 32 MB

    reduce_convert_x<<<RBLOCKS, 256, 0, stream>>>(x, xb, px);
    reduce_abs_w<<<RBLOCKS, 256, 0, stream>>>(w, pw);
    finalize_scales<<<1, 256, 0, stream>>>(px, pw, scales);
    quantize_w<<<4096, 256, 0, stream>>>(w, qb, scales);

    dim3 grid(N / 128, M / 128);
    gemm_bt<<<grid, 256, 0, stream>>>(xb, qb, bias, scales, out);
}

// Round 3
// 333.322 us; speedup vs baseline: 1.2133x; 1.0063x over previous
//
#include <hip/hip_runtime.h>
#include <hip/hip_bf16.h>

#define AS1 __attribute__((address_space(1)))
#define AS3 __attribute__((address_space(3)))

typedef __attribute__((ext_vector_type(8))) short bfrag8;   // 8 bf16 in 4 VGPRs
typedef __attribute__((ext_vector_type(4))) float floatx4;  // MFMA accumulator

static constexpr int M = 4096, N = 4096, K = 4096;
static constexpr long long NELEM = 16777216LL;   // 4096*4096
static constexpr long long N4 = NELEM / 4;       // float4 count = 4,194,304
static constexpr int RB = 2048;                  // reduction blocks per array
// threads per array = RB*256 = 524,288 ; float4 per thread = 8

// ---------- round-to-nearest-even fp32 -> bf16 ----------
__device__ __forceinline__ unsigned short f2bf(float f) {
    unsigned int u = __float_as_uint(f);
    u += 0x7FFFu + ((u >> 16) & 1u);
    return (unsigned short)(u >> 16);
}

// ---------- block reduce (double) -> value on thread 0 ----------
__device__ __forceinline__ double block_reduce(double s) {
    #pragma unroll
    for (int off = 32; off > 0; off >>= 1) s += __shfl_down(s, off, 64);
    __shared__ double part[4];
    int lane = threadIdx.x & 63, wv = threadIdx.x >> 6;
    if (lane == 0) part[wv] = s;
    __syncthreads();
    return part[0] + part[1] + part[2] + part[3];
}

// ---------- fused: blocks [0,RB) -> sum|x| + convert x->bf16 ; [RB,2RB) -> sum|w| ----------
__global__ __launch_bounds__(256) void prep_reduce(
        const float* __restrict__ x, unsigned short* __restrict__ xb,
        const float* __restrict__ w,
        double* __restrict__ px, double* __restrict__ pw) {
    const int b = blockIdx.x;
    const bool isW = b >= RB;
    const int rb = isW ? b - RB : b;
    const long long base = (long long)rb * 256 + threadIdx.x;  // float4 index
    const long long S = (long long)RB * 256;                   // stride = 524,288

    const float4* src = (const float4*)(isW ? w : x);
    float4 v[8];
    #pragma unroll
    for (int i = 0; i < 8; i++) v[i] = src[base + i * S];      // 8 independent loads

    double s = 0.0;
    #pragma unroll
    for (int i = 0; i < 8; i++) {
        s += (double)fabsf(v[i].x); s += (double)fabsf(v[i].y);
        s += (double)fabsf(v[i].z); s += (double)fabsf(v[i].w);
    }

    if (!isW) {
        ushort4* xb4 = (ushort4*)xb;
        #pragma unroll
        for (int i = 0; i < 8; i++) {
            ushort4 r;
            r.x = f2bf(v[i].x); r.y = f2bf(v[i].y);
            r.z = f2bf(v[i].z); r.w = f2bf(v[i].w);
            xb4[base + i * S] = r;
        }
    }

    double bs = block_reduce(s);
    if (threadIdx.x == 0) (isW ? pw : px)[rb] = bs;
}

// ---------- finalize: partials -> float scales ----------
__global__ void finalize_scales(const double* __restrict__ px,
                                const double* __restrict__ pw,
                                float* __restrict__ scales) {
    int t = threadIdx.x;  // 256 threads, RB=2048 partials each
    double sx = 0.0, sw = 0.0;
    #pragma unroll
    for (int i = 0; i < 8; i++) { sx += px[t + i * 256]; sw += pw[t + i * 256]; }
    #pragma unroll
    for (int off = 32; off > 0; off >>= 1) {
        sx += __shfl_down(sx, off, 64);
        sw += __shfl_down(sw, off, 64);
    }
    __shared__ double ax[4], aw[4];
    int lane = t & 63, wv = t >> 6;
    if (lane == 0) { ax[wv] = sx; aw[wv] = sw; }
    __syncthreads();
    if (t == 0) {
        double fsx = ax[0] + ax[1] + ax[2] + ax[3];
        double fsw = aw[0] + aw[1] + aw[2] + aw[3];
        scales[0] = (float)fmax(fsw / (double)NELEM, 1e-8);  // weight scale
        scales[1] = (float)fmax(fsx / (double)NELEM, 1e-8);  // input scale
    }
}

// ---------- ternary quantize W -> bf16 {-1,0,+1} ----------
__device__ __forceinline__ unsigned short tq(float v, float scale_f) {
    float wn = v / scale_f;                       // match reference fp32 division
    if (fabsf(wn) > 0.5f)
        return (unsigned short)(0x3F80u | ((__float_as_uint(v) >> 16) & 0x8000u));
    return 0;
}

__global__ __launch_bounds__(256) void quantize_w(
        const float* __restrict__ w, unsigned short* __restrict__ qb,
        const float* __restrict__ scales) {
    const float scale_f = scales[0];
    const long long base = (long long)blockIdx.x * 256 + threadIdx.x;
    const long long S = (long long)RB * 256;
    const float4* w4 = (const float4*)w;
    ushort4* q4 = (ushort4*)qb;
    float4 v[8];
    #pragma unroll
    for (int i = 0; i < 8; i++) v[i] = w4[base + i * S];
    #pragma unroll
    for (int i = 0; i < 8; i++) {
        ushort4 r;
        r.x = tq(v[i].x, scale_f); r.y = tq(v[i].y, scale_f);
        r.z = tq(v[i].z, scale_f); r.w = tq(v[i].w, scale_f);
        q4[base + i * S] = r;
    }
}

// ---------- m97-style bf16 GEMM with XOR-swizzled LDS (unchanged from R2) ----------
// out[m][n] = (sum_k A[m][k]*B[n][k]) * wscale + bias[n]*iscale
// LDS row r (128B) holds its 8 k-chunks permuted: chunk j at slot j^(r&7).
// Staging permutes the *global* source per lane (global_load_lds forces LDS
// dst = base + lane*16); reads apply the inverse. Bank census: 8 dwords/bank
// per wave64 b128 read (floor) -> SQ_LDS_BANK_CONFLICT = 0 (verified R2).
__global__ __launch_bounds__(256) void gemm_bt(
        const unsigned short* __restrict__ A,
        const unsigned short* __restrict__ B,
        const float* __restrict__ bias,
        const float* __restrict__ scales,   // [0]=wscale, [1]=iscale
        float* __restrict__ out) {
    __shared__ unsigned short lds[2 * 128 * 64];  // A tile 16KB + B tile 16KB
    const char* ldsA = (const char*)lds;
    const char* ldsB = (const char*)lds + 16384;

    const int tid = threadIdx.x;
    const int lane = tid & 63;
    const int wv = tid >> 6;            // wave 0..3
    const int wm = wv & 1;              // 2x2 wave grid, 64x64 each
    const int wn = wv >> 1;
    const int col16 = lane & 15;
    const int quad = lane >> 4;

    const int m0 = blockIdx.y * 128;
    const int n0 = blockIdx.x * 128;

    const int srow = lane >> 3;                      // 0..7 within chunk
    const int scol = ((lane & 7) ^ srow) * 8;        // swizzled k-offset (elements)

    floatx4 acc[4][4];
    #pragma unroll
    for (int i = 0; i < 4; i++)
        #pragma unroll
        for (int j = 0; j < 4; j++)
            acc[i][j] = (floatx4)0.0f;

    for (int k0 = 0; k0 < K; k0 += 64) {
        #pragma unroll
        for (int j = 0; j < 4; j++) {
            const int c = wv * 4 + j;            // 0..15
            const int row = c * 8 + srow;        // 0..127
            const unsigned short* ga = A + (size_t)(m0 + row) * K + k0 + scol;
            const unsigned short* gb = B + (size_t)(n0 + row) * K + k0 + scol;
            char* la = (char*)lds + c * 1024 + lane * 16;
            char* lb = (char*)lds + 16384 + c * 1024 + lane * 16;
            __builtin_amdgcn_global_load_lds((const AS1 void*)ga, (AS3 void*)la, 16, 0, 0);
            __builtin_amdgcn_global_load_lds((const AS1 void*)gb, (AS3 void*)lb, 16, 0, 0);
        }
        __syncthreads();

        #pragma unroll
        for (int kk = 0; kk < 64; kk += 32) {
            const int kc = (kk >> 3) + quad;             // k-chunk index 0..7
            const int sw = (kc ^ (col16 & 7)) << 4;      // swizzled byte offset in row
            bfrag8 af[4], bfr[4];
            #pragma unroll
            for (int i = 0; i < 4; i++) {
                const int ra = wm * 64 + i * 16 + col16;
                const int rb = wn * 64 + i * 16 + col16;
                af[i]  = *(const bfrag8*)(ldsA + ra * 128 + sw);
                bfr[i] = *(const bfrag8*)(ldsB + rb * 128 + sw);
            }
            #pragma unroll
            for (int i = 0; i < 4; i++)
                #pragma unroll
                for (int j = 0; j < 4; j++)
                    acc[i][j] = __builtin_amdgcn_mfma_f32_16x16x32_bf16(af[i], bfr[j], acc[i][j], 0, 0, 0);
        }
        __syncthreads();
    }

    const float wscale = scales[0];
    const float iscale = scales[1];

    float bv[4];
    #pragma unroll
    for (int j = 0; j < 4; j++)
        bv[j] = bias[n0 + wn * 64 + j * 16 + col16] * iscale;

    #pragma unroll
    for (int i = 0; i < 4; i++) {
        const int mbase = m0 + wm * 64 + i * 16 + quad * 4;
        #pragma unroll
        for (int j = 0; j < 4; j++) {
            const int n = n0 + wn * 64 + j * 16 + col16;
            #pragma unroll
            for (int r = 0; r < 4; r++)
                out[(size_t)(mbase + r) * N + n] = acc[i][j][r] * wscale + bv[j];
        }
    }
}

extern "C" void kernel_launch(void* const* d_in, const int* in_sizes, int n_in,
                              void* d_out, int out_size, void* d_ws, size_t ws_size,
                              hipStream_t stream) {
    const float* x    = (const float*)d_in[0];   // (2,2048,4096) fp32
    const float* w    = (const float*)d_in[1];   // (4096,4096) fp32
    const float* bias = (const float*)d_in[2];   // (4096,) fp32
    float* out = (float*)d_out;                  // (2,2048,4096) fp32

    char* ws = (char*)d_ws;
    float* scales = (float*)ws;                                            // 8 B
    unsigned short* xb = (unsigned short*)(ws + 16384);                    // 32 MB bf16 x
    unsigned short* qb = (unsigned short*)(ws + 16384 + (size_t)NELEM * 2);// 32 MB bf16 qW
    // Partials live at the head of the qb region: written by prep_reduce,
    // consumed by finalize_scales BEFORE quantize_w overwrites qb (stream order).
    double* px = (double*)qb;                                              // 16 KB
    double* pw = px + RB;                                                  // 16 KB

    prep_reduce<<<2 * RB, 256, 0, stream>>>(x, xb, w, px, pw);
    finalize_scales<<<1, 256, 0, stream>>>(px, pw, scales);
    quantize_w<<<RB, 256, 0, stream>>>(w, qb, scales);

    dim3 grid(N / 128, M / 128);
    gemm_bt<<<grid, 256, 0, stream>>>(xb, qb, bias, scales, out);
}